// Round 4
// baseline (614.667 us; speedup 1.0000x reference)
//
#include <hip/hip_runtime.h>
#include <hip/hip_bf16.h>

typedef __hip_bfloat16 bf16;
typedef short bf16x8 __attribute__((ext_vector_type(8)));   // 8 bf16 = 16B (4 VGPRs)
typedef float f32x4 __attribute__((ext_vector_type(4)));

#define ND     40962
#define NUP    163842
#define NBATCH 2
#define NTC    2561            // ceil(NUP/64)  conv M-tiles (64 nodes/block)
#define NT64   2561
#define BN_EPS 1e-5
#define SLOPE  0.2f

// ---- ws layout (bytes), all 256-aligned ----
#define OFF_W1P   0ull                      // 64*896*2  = 114688
#define OFF_W2P   114688ull                 // 64*448*2  = 57344
#define OFF_STATS 172032ull                 // sc[64]+sh[64] fp32 = 512
#define OFF_H     173056ull                 // h bf16: 2*40962*64*2 = 10486272 ; partials alias
#define OFF_P2    (OFF_H + 2622464ull)      // p2 (64KB) aliases h tail
#define OFF_XCAT  10659328ull               // x_cat bf16: 2*163842*128*2 = 83887104 ; z1 aliases
#define OFF_Y     94546432ull               // y bf16: 2*163842*64*2 = 41943552
// total ≈ 136.5 MB

__device__ __forceinline__ void gload_lds16(const void* g, void* l) {
  __builtin_amdgcn_global_load_lds(
      (const __attribute__((address_space(1))) void*)g,
      (__attribute__((address_space(3))) void*)l, 16, 0, 0);
}

__device__ __forceinline__ float lrelu(float v) { return v >= 0.0f ? v : SLOPE * v; }

// ---------------- K0: permute + bf16-convert conv weights: f' = kk*C + c ----------------
__global__ __launch_bounds__(256) void k_permw(const float* __restrict__ w1,
                                               const float* __restrict__ w2,
                                               bf16* __restrict__ w1p, bf16* __restrict__ w2p) {
  int t = blockIdx.x * 256 + threadIdx.x;
  if (t < 64 * 896) {
    int o = t / 896, f = t % 896;
    int kk = f / 128, c = f % 128;
    w1p[t] = __float2bfloat16(w1[o * 896 + c * 7 + kk]);
  } else if (t < 64 * 896 + 64 * 448) {
    int idx = t - 64 * 896;
    int o = idx / 448, f = idx % 448;
    int kk = f / 64, c = f % 64;
    w2p[idx] = __float2bfloat16(w2[o * 448 + c * 7 + kk]);
  }
}

// ---------------- K1: h[b,n,o] = sum_c x1[b,c,n]*wfc[o,c] + bfc[o]  (bf16 out, node-major) ----
__global__ __launch_bounds__(256) void k_h(const float* __restrict__ x1,
                                           const float* __restrict__ wfc,
                                           const float* __restrict__ bfc,
                                           bf16* __restrict__ h) {
  __shared__ float wl[128 * 64];   // wl[c*64+o]
  __shared__ float bl[64];
  int tid = threadIdx.x, b = blockIdx.y;
  for (int i = tid; i < 8192; i += 256) { int o = i >> 7, c = i & 127; wl[c * 64 + o] = wfc[i]; }
  if (tid < 64) bl[tid] = bfc[tid];
  __syncthreads();
  int n = blockIdx.x * 256 + tid;
  int nc = n < ND ? n : ND - 1;
  float acc[64];
#pragma unroll
  for (int o = 0; o < 64; ++o) acc[o] = bl[o];
#pragma unroll 4
  for (int c = 0; c < 128; ++c) {
    float xv = x1[((size_t)b * 128 + c) * (size_t)ND + nc];
    const f32x4* wrow = (const f32x4*)(wl + c * 64);
#pragma unroll
    for (int og = 0; og < 16; ++og) {
      f32x4 wv = wrow[og];
      acc[og * 4 + 0] = fmaf(xv, wv[0], acc[og * 4 + 0]);
      acc[og * 4 + 1] = fmaf(xv, wv[1], acc[og * 4 + 1]);
      acc[og * 4 + 2] = fmaf(xv, wv[2], acc[og * 4 + 2]);
      acc[og * 4 + 3] = fmaf(xv, wv[3], acc[og * 4 + 3]);
    }
  }
  if (n < ND) {
    bf16* hp = h + ((size_t)b * ND + n) * 64;
#pragma unroll
    for (int og = 0; og < 8; ++og) {
      union { bf16x8 v; bf16 e[8]; } u;
#pragma unroll
      for (int j = 0; j < 8; ++j) u.e[j] = __float2bfloat16(acc[og * 8 + j]);
      ((bf16x8*)hp)[og] = u.v;
    }
  }
}

// ---------------- K2: x_cat[b,m,0:64] = 0.5*(h[n0]+h[n1]); x_cat[b,m,64:128] = x2[b,:,m] ------
__global__ __launch_bounds__(256) void k_xcat(const float* __restrict__ x2,
                                              const bf16* __restrict__ h,
                                              const int* __restrict__ upn,
                                              bf16* __restrict__ xcat) {
  __shared__ float tt[64][65];
  __shared__ int un[64][2];
  int tid = threadIdx.x, b = blockIdx.y;
  int m0 = blockIdx.x * 64;
#pragma unroll
  for (int i = 0; i < 16; ++i) {
    int c = i * 4 + (tid >> 6);
    int ml = tid & 63;
    int m = m0 + ml; if (m >= NUP) m = NUP - 1;
    tt[c][ml] = x2[((size_t)b * 64 + c) * (size_t)NUP + m];
  }
  if (tid < 128) {
    int ml = tid >> 1, w = tid & 1;
    int m = m0 + ml; if (m >= NUP) m = NUP - 1;
    un[ml][w] = upn[(size_t)m * 2 + w];
  }
  __syncthreads();
  int ln = tid >> 2, p = tid & 3;
  int m = m0 + ln;
  if (m >= NUP) return;
  bf16* dst = xcat + ((size_t)b * NUP + m) * 128;
  if (p < 2) {
    int c0 = p * 32;
    const bf16* h0 = h + ((size_t)b * ND + un[ln][0]) * 64 + c0;
    const bf16* h1 = h + ((size_t)b * ND + un[ln][1]) * 64 + c0;
#pragma unroll
    for (int q = 0; q < 4; ++q) {
      union { bf16x8 v; bf16 e[8]; } a, bb, o_;
      a.v = ((const bf16x8*)h0)[q];
      bb.v = ((const bf16x8*)h1)[q];
#pragma unroll
      for (int j = 0; j < 8; ++j)
        o_.e[j] = __float2bfloat16(0.5f * (__bfloat162float(a.e[j]) + __bfloat162float(bb.e[j])));
      ((bf16x8*)(dst + c0))[q] = o_.v;
    }
  } else {
    int c0 = (p - 2) * 32;
#pragma unroll
    for (int q = 0; q < 4; ++q) {
      union { bf16x8 v; bf16 e[8]; } o_;
#pragma unroll
      for (int j = 0; j < 8; ++j) o_.e[j] = __float2bfloat16(tt[c0 + q * 8 + j][ln]);
      ((bf16x8*)(dst + 64 + c0))[q] = o_.v;
    }
  }
}

// ---------------- K3: gathered conv (GEMM, K = 7*CIN), wave-private DMA double-buffer --------
// Fix vs r3: per kk, B-loads are issued BEFORE STAGE(kk+1), so the implicit waitcnt on B
// consumption (B older than the new DMA) never drains the prefetch; explicit counted
// vmcnt(NB+STAGE_N) orders STAGE(kk) completion before its ds_reads. 16 nodes/wave keeps
// LDS at 36.6KB (CIN=128) -> 4 blocks/CU. No __syncthreads in the K-loop (wave-private LDS).
template <int CIN>
__global__ __launch_bounds__(256) void k_conv(const bf16* __restrict__ x,
                                              const int* __restrict__ neigh,
                                              const bf16* __restrict__ wp,
                                              const float* __restrict__ bias,
                                              bf16* __restrict__ y,
                                              float* __restrict__ partials) {
  constexpr int SLOTS   = CIN / 8;          // 16B slots per row (16 or 8)
  constexpr int STAGE_N = CIN / 32;         // DMA instrs per wave per kk (4 or 2)
  constexpr int ROWS_PI = 512 / CIN;        // rows per 1KB DMA instr (4 or 8)
  constexpr int KS      = CIN / 32;         // MFMA K-steps (4 or 2)

  __shared__ bf16 lA[2][4][16 * CIN];       // [buf][wave][row*CIN]  32KB / 16KB
  __shared__ int nbl[4][16 * 7];
  __shared__ float lred[4][2][64];

  int tid = threadIdx.x, b = blockIdx.y;
  int n0 = blockIdx.x * 64;
  int wv = tid >> 6, lane = tid & 63;
  int l15 = lane & 15, l4 = lane >> 4;

  // wave-private neighbor table (112 ints)
  {
    int base7 = (n0 + wv * 16) * 7;
    int gmax = NUP * 7 - 1;
#pragma unroll
    for (int j0 = 0; j0 < 2; ++j0) {
      int j = j0 * 64 + lane;
      if (j < 112) {
        int gi = base7 + j;
        nbl[wv][j] = neigh[gi <= gmax ? gi : gmax];
      }
    }
  }

  f32x4 acc[4];
#pragma unroll
  for (int ot = 0; ot < 4; ++ot) {
    float bv = bias[ot * 16 + l15];
    acc[ot] = (f32x4){bv, bv, bv, bv};
  }

  const bf16* xb = x + (size_t)b * NUP * CIN;
  const int r_in = lane / (SLOTS);              // row offset within 1KB instr
  const int s_in = lane % SLOTS;                // slot within row

  auto STAGE = [&](int buf, int kk) {
#pragma unroll
    for (int i = 0; i < STAGE_N; ++i) {
      int r = i * ROWS_PI + r_in;
      int g = s_in ^ (r & 7);
      int node = nbl[wv][r * 7 + kk];
      gload_lds16(xb + (size_t)node * CIN + g * 8, &lA[buf][wv][i * 512]);
    }
  };

  STAGE(0, 0);

  for (int kk = 0; kk < 7; ++kk) {
    int buf = kk & 1;
    // B fragments for this kk FIRST (older than the prefetch DMA in the vm FIFO)
    const bf16* wk = wp + kk * CIN + l15 * (7 * CIN) + l4 * 8;
    bf16x8 bfr[4][KS];
#pragma unroll
    for (int ot = 0; ot < 4; ++ot)
#pragma unroll
      for (int ks = 0; ks < KS; ++ks)
        bfr[ot][ks] = *(const bf16x8*)(wk + ot * (16 * 7 * CIN) + ks * 32);

    __builtin_amdgcn_sched_barrier(0);
    if (kk < 6) STAGE(buf ^ 1, kk + 1);
    __builtin_amdgcn_sched_barrier(0);
    // wait for STAGE(kk) (issued last iter, older than B(kk) and STAGE(kk+1)):
    // outstanding allowed = NB (=4*KS) B-loads + STAGE_N new DMA
    if constexpr (CIN == 128) {
      if (kk < 6) asm volatile("s_waitcnt vmcnt(20)" ::: "memory");
      else        asm volatile("s_waitcnt vmcnt(16)" ::: "memory");
    } else {
      if (kk < 6) asm volatile("s_waitcnt vmcnt(10)" ::: "memory");
      else        asm volatile("s_waitcnt vmcnt(8)" ::: "memory");
    }
    __builtin_amdgcn_sched_barrier(0);

#pragma unroll
    for (int ks = 0; ks < KS; ++ks) {
      int r = l15;
      int s = (ks * 4 + l4) ^ (r & 7);
      bf16x8 a = *(const bf16x8*)(&lA[buf][wv][r * CIN + s * 8]);
#pragma unroll
      for (int ot = 0; ot < 4; ++ot)
        acc[ot] = __builtin_amdgcn_mfma_f32_16x16x32_bf16(a, bfr[ot][ks], acc[ot], 0, 0, 0);
    }
  }

  // store y (bf16) + per-channel partial sums (valid nodes only)
  float s[4], q[4];
#pragma unroll
  for (int ot = 0; ot < 4; ++ot) { s[ot] = 0.0f; q[ot] = 0.0f; }
  bf16* yb = y + (size_t)b * NUP * 64;
  int nodebase = n0 + wv * 16 + l4 * 4;
#pragma unroll
  for (int i = 0; i < 4; ++i) {
    int node = nodebase + i;
    bool ok = node < NUP;
#pragma unroll
    for (int ot = 0; ot < 4; ++ot) {
      float v = acc[ot][i];
      if (ok) {
        yb[(size_t)node * 64 + ot * 16 + l15] = __float2bfloat16(v);
        s[ot] += v; q[ot] += v * v;
      }
    }
  }
#pragma unroll
  for (int ot = 0; ot < 4; ++ot) {
    s[ot] += __shfl_xor(s[ot], 16); s[ot] += __shfl_xor(s[ot], 32);
    q[ot] += __shfl_xor(q[ot], 16); q[ot] += __shfl_xor(q[ot], 32);
  }
  if (lane < 16) {
#pragma unroll
    for (int ot = 0; ot < 4; ++ot) {
      lred[wv][0][ot * 16 + lane] = s[ot];
      lred[wv][1][ot * 16 + lane] = q[ot];
    }
  }
  __syncthreads();
  if (tid < 128) {
    int which = tid >> 6, c = tid & 63;
    float p = lred[0][which][c] + lred[1][which][c] + lred[2][which][c] + lred[3][which][c];
    partials[((size_t)b * gridDim.x + blockIdx.x) * 128 + which * 64 + c] = p;
  }
}

// ---------------- K4a: tree-reduce partials (nblk x 128) -> (128 x 128) ----------------------
__global__ __launch_bounds__(256) void k_red1(const float* __restrict__ p, int nblk,
                                              float* __restrict__ p2) {
  int g = blockIdx.x * 2 + threadIdx.x / 128;
  int j = threadIdx.x & 127;
  float a = 0.0f;
  for (int r = g; r < nblk; r += 128) a += p[(size_t)r * 128 + j];
  p2[(size_t)g * 128 + j] = a;
}

// ---------------- K4b: finalize BN: sc = g*rsqrt(var+eps), sh = beta - mean*sc ---------------
__global__ __launch_bounds__(128) void k_stats(const float* __restrict__ p2,
                                               const float* __restrict__ g,
                                               const float* __restrict__ be,
                                               float* __restrict__ sc, float* __restrict__ sh) {
  __shared__ double red[128];
  int j = threadIdx.x;
  double a = 0.0;
  for (int r = 0; r < 128; ++r) a += (double)p2[r * 128 + j];
  red[j] = a;
  __syncthreads();
  if (j < 64) {
    double M = (double)NBATCH * (double)NUP;
    double mean = red[j] / M;
    double var = red[64 + j] / M - mean * mean;
    float s = g[j] * (float)(1.0 / sqrt(var + BN_EPS));
    sc[j] = s;
    sh[j] = be[j] - (float)mean * s;
  }
}

// ---------------- K5: z = bf16(lrelu(y*sc + sh))  (y bf16 node-major) ------------------------
__global__ __launch_bounds__(256) void k_bnapply(const bf16* __restrict__ y,
                                                 const float* __restrict__ sc,
                                                 const float* __restrict__ sh,
                                                 bf16* __restrict__ z) {
  __shared__ float ssc[64], ssh[64];
  int tid = threadIdx.x;
  if (tid < 64) { ssc[tid] = sc[tid]; ssh[tid] = sh[tid]; }
  __syncthreads();
  size_t e = ((size_t)blockIdx.x * 256 + tid) * 8;
  if (e >= (size_t)NBATCH * NUP * 64) return;
  int c0 = (int)(e & 63);
  union { bf16x8 v; bf16 el[8]; } in_, o_;
  in_.v = *(const bf16x8*)(y + e);
#pragma unroll
  for (int j = 0; j < 8; ++j) {
    float f = __bfloat162float(in_.el[j]);
    o_.el[j] = __float2bfloat16(lrelu(fmaf(f, ssc[c0 + j], ssh[c0 + j])));
  }
  *(bf16x8*)(z + e) = o_.v;
}

// ---------------- K8: out[b,c,n] = lrelu(y[b,n,c]*sc+sh)  (transpose to channel-major) -------
__global__ __launch_bounds__(256) void k_final(const bf16* __restrict__ y,
                                               const float* __restrict__ sc,
                                               const float* __restrict__ sh,
                                               float* __restrict__ out) {
  __shared__ float t[64][65];
  __shared__ float ssc[64], ssh[64];
  int tid = threadIdx.x, b = blockIdx.y;
  int n0 = blockIdx.x * 64;
  if (tid < 64) { ssc[tid] = sc[tid]; ssh[tid] = sh[tid]; }
  __syncthreads();
  int ln = tid >> 2, qc = tid & 3;
  int n = n0 + ln; if (n >= NUP) n = NUP - 1;
  const bf16* yp = y + ((size_t)b * NUP + n) * 64 + qc * 16;
  union { bf16x8 v; bf16 el[8]; } v0, v1;
  v0.v = ((const bf16x8*)yp)[0];
  v1.v = ((const bf16x8*)yp)[1];
#pragma unroll
  for (int j = 0; j < 8; ++j) {
    int c = qc * 16 + j;
    t[ln][c] = lrelu(fmaf(__bfloat162float(v0.el[j]), ssc[c], ssh[c]));
  }
#pragma unroll
  for (int j = 0; j < 8; ++j) {
    int c = qc * 16 + 8 + j;
    t[ln][c] = lrelu(fmaf(__bfloat162float(v1.el[j]), ssc[c], ssh[c]));
  }
  __syncthreads();
  int nl = tid & 63;
  int nn = n0 + nl;
  if (nn >= NUP) return;
#pragma unroll
  for (int i = 0; i < 16; ++i) {
    int c = i * 4 + (tid >> 6);
    out[((size_t)b * 64 + c) * (size_t)NUP + nn] = t[nl][c];
  }
}

extern "C" void kernel_launch(void* const* d_in, const int* in_sizes, int n_in,
                              void* d_out, int out_size, void* d_ws, size_t ws_size,
                              hipStream_t stream) {
  const float* x1      = (const float*)d_in[0];
  const float* x2      = (const float*)d_in[1];
  const float* up_fc_w = (const float*)d_in[2];
  const float* up_fc_b = (const float*)d_in[3];
  const float* conv1_w = (const float*)d_in[4];
  const float* conv1_b = (const float*)d_in[5];
  const float* bn1_g   = (const float*)d_in[6];
  const float* bn1_b   = (const float*)d_in[7];
  const float* conv2_w = (const float*)d_in[8];
  const float* conv2_b = (const float*)d_in[9];
  const float* bn2_g   = (const float*)d_in[10];
  const float* bn2_b   = (const float*)d_in[11];
  const int* up_neigh  = (const int*)d_in[12];
  const int* conv_nei  = (const int*)d_in[13];

  char* ws = (char*)d_ws;
  bf16*  w1p  = (bf16*)(ws + OFF_W1P);
  bf16*  w2p  = (bf16*)(ws + OFF_W2P);
  float* sc   = (float*)(ws + OFF_STATS);
  float* sh   = sc + 64;
  bf16*  h    = (bf16*)(ws + OFF_H);
  float* part = (float*)(ws + OFF_H);      // aliases h (h dead after k_xcat)
  float* p2   = (float*)(ws + OFF_P2);
  bf16*  xcat = (bf16*)(ws + OFF_XCAT);
  bf16*  z1   = (bf16*)(ws + OFF_XCAT);    // aliases xcat (dead after conv1)
  bf16*  y    = (bf16*)(ws + OFF_Y);
  float* out  = (float*)d_out;

  k_permw<<<336, 256, 0, stream>>>(conv1_w, conv2_w, w1p, w2p);
  k_h<<<dim3(161, 2), 256, 0, stream>>>(x1, up_fc_w, up_fc_b, h);
  k_xcat<<<dim3(NT64, 2), 256, 0, stream>>>(x2, h, up_neigh, xcat);
  k_conv<128><<<dim3(NTC, 2), 256, 0, stream>>>(xcat, conv_nei, w1p, conv1_b, y, part);
  k_red1<<<64, 256, 0, stream>>>(part, 2 * NTC, p2);
  k_stats<<<1, 128, 0, stream>>>(p2, bn1_g, bn1_b, sc, sh);
  k_bnapply<<<10241, 256, 0, stream>>>(y, sc, sh, z1);
  k_conv<64><<<dim3(NTC, 2), 256, 0, stream>>>(z1, conv_nei, w2p, conv2_b, y, part);
  k_red1<<<64, 256, 0, stream>>>(part, 2 * NTC, p2);
  k_stats<<<1, 128, 0, stream>>>(p2, bn2_g, bn2_b, sc, sh);
  k_final<<<dim3(NT64, 2), 256, 0, stream>>>(y, sc, sh, out);
}

// Round 5
// 393.623 us; speedup vs baseline: 1.5616x; 1.5616x over previous
//
#include <hip/hip_runtime.h>
#include <hip/hip_bf16.h>

typedef __hip_bfloat16 bf16;
typedef short bf16x8 __attribute__((ext_vector_type(8)));   // 8 bf16 = 16B (4 VGPRs)
typedef float f32x4 __attribute__((ext_vector_type(4)));

#define ND     40962
#define NUP    163842
#define NBATCH 2
#define NTC    2561            // ceil(NUP/64)  conv M-tiles (64 nodes/block)
#define NT64   2561
#define BN_EPS 1e-5
#define SLOPE  0.2f

// ---- ws layout (bytes), all 256-aligned ----
#define OFF_W1P   0ull                      // 64*896*2  = 114688
#define OFF_W2P   114688ull                 // 64*448*2  = 57344
#define OFF_STATS 172032ull                 // sc[64]+sh[64] fp32 = 512
#define OFF_H     173056ull                 // h bf16: 2*40962*64*2 = 10486272 ; partials alias
#define OFF_P2    (OFF_H + 2622464ull)      // p2 (64KB) aliases h tail
#define OFF_XCAT  10659328ull               // x_cat bf16: 2*163842*128*2 = 83887104 ; z1 aliases
#define OFF_Y     94546432ull               // y bf16: 2*163842*64*2 = 41943552
// total ≈ 136.5 MB

__device__ __forceinline__ void gload_lds16(const void* g, void* l) {
  __builtin_amdgcn_global_load_lds(
      (const __attribute__((address_space(1))) void*)g,
      (__attribute__((address_space(3))) void*)l, 16, 0, 0);
}

__device__ __forceinline__ float lrelu(float v) { return v >= 0.0f ? v : SLOPE * v; }

// ---------------- K0: permute + bf16-convert conv weights: f' = kk*C + c ----------------
__global__ __launch_bounds__(256) void k_permw(const float* __restrict__ w1,
                                               const float* __restrict__ w2,
                                               bf16* __restrict__ w1p, bf16* __restrict__ w2p) {
  int t = blockIdx.x * 256 + threadIdx.x;
  if (t < 64 * 896) {
    int o = t / 896, f = t % 896;
    int kk = f / 128, c = f % 128;
    w1p[t] = __float2bfloat16(w1[o * 896 + c * 7 + kk]);
  } else if (t < 64 * 896 + 64 * 448) {
    int idx = t - 64 * 896;
    int o = idx / 448, f = idx % 448;
    int kk = f / 64, c = f % 64;
    w2p[idx] = __float2bfloat16(w2[o * 448 + c * 7 + kk]);
  }
}

// ---------------- K1: h[b,n,o] = sum_c x1[b,c,n]*wfc[o,c] + bfc[o]  (bf16 out, node-major) ----
__global__ __launch_bounds__(256) void k_h(const float* __restrict__ x1,
                                           const float* __restrict__ wfc,
                                           const float* __restrict__ bfc,
                                           bf16* __restrict__ h) {
  __shared__ float wl[128 * 64];   // wl[c*64+o]
  __shared__ float bl[64];
  int tid = threadIdx.x, b = blockIdx.y;
  for (int i = tid; i < 8192; i += 256) { int o = i >> 7, c = i & 127; wl[c * 64 + o] = wfc[i]; }
  if (tid < 64) bl[tid] = bfc[tid];
  __syncthreads();
  int n = blockIdx.x * 256 + tid;
  int nc = n < ND ? n : ND - 1;
  float acc[64];
#pragma unroll
  for (int o = 0; o < 64; ++o) acc[o] = bl[o];
#pragma unroll 4
  for (int c = 0; c < 128; ++c) {
    float xv = x1[((size_t)b * 128 + c) * (size_t)ND + nc];
    const f32x4* wrow = (const f32x4*)(wl + c * 64);
#pragma unroll
    for (int og = 0; og < 16; ++og) {
      f32x4 wv = wrow[og];
      acc[og * 4 + 0] = fmaf(xv, wv[0], acc[og * 4 + 0]);
      acc[og * 4 + 1] = fmaf(xv, wv[1], acc[og * 4 + 1]);
      acc[og * 4 + 2] = fmaf(xv, wv[2], acc[og * 4 + 2]);
      acc[og * 4 + 3] = fmaf(xv, wv[3], acc[og * 4 + 3]);
    }
  }
  if (n < ND) {
    bf16* hp = h + ((size_t)b * ND + n) * 64;
#pragma unroll
    for (int og = 0; og < 8; ++og) {
      union { bf16x8 v; bf16 e[8]; } u;
#pragma unroll
      for (int j = 0; j < 8; ++j) u.e[j] = __float2bfloat16(acc[og * 8 + j]);
      ((bf16x8*)hp)[og] = u.v;
    }
  }
}

// ---------------- K2: x_cat[b,m,0:64] = 0.5*(h[n0]+h[n1]); x_cat[b,m,64:128] = x2[b,:,m] ------
__global__ __launch_bounds__(256) void k_xcat(const float* __restrict__ x2,
                                              const bf16* __restrict__ h,
                                              const int* __restrict__ upn,
                                              bf16* __restrict__ xcat) {
  __shared__ float tt[64][65];
  __shared__ int un[64][2];
  int tid = threadIdx.x, b = blockIdx.y;
  int m0 = blockIdx.x * 64;
#pragma unroll
  for (int i = 0; i < 16; ++i) {
    int c = i * 4 + (tid >> 6);
    int ml = tid & 63;
    int m = m0 + ml; if (m >= NUP) m = NUP - 1;
    tt[c][ml] = x2[((size_t)b * 64 + c) * (size_t)NUP + m];
  }
  if (tid < 128) {
    int ml = tid >> 1, w = tid & 1;
    int m = m0 + ml; if (m >= NUP) m = NUP - 1;
    un[ml][w] = upn[(size_t)m * 2 + w];
  }
  __syncthreads();
  int ln = tid >> 2, p = tid & 3;
  int m = m0 + ln;
  if (m >= NUP) return;
  bf16* dst = xcat + ((size_t)b * NUP + m) * 128;
  if (p < 2) {
    int c0 = p * 32;
    const bf16* h0 = h + ((size_t)b * ND + un[ln][0]) * 64 + c0;
    const bf16* h1 = h + ((size_t)b * ND + un[ln][1]) * 64 + c0;
#pragma unroll
    for (int q = 0; q < 4; ++q) {
      union { bf16x8 v; bf16 e[8]; } a, bb, o_;
      a.v = ((const bf16x8*)h0)[q];
      bb.v = ((const bf16x8*)h1)[q];
#pragma unroll
      for (int j = 0; j < 8; ++j)
        o_.e[j] = __float2bfloat16(0.5f * (__bfloat162float(a.e[j]) + __bfloat162float(bb.e[j])));
      ((bf16x8*)(dst + c0))[q] = o_.v;
    }
  } else {
    int c0 = (p - 2) * 32;
#pragma unroll
    for (int q = 0; q < 4; ++q) {
      union { bf16x8 v; bf16 e[8]; } o_;
#pragma unroll
      for (int j = 0; j < 8; ++j) o_.e[j] = __float2bfloat16(tt[c0 + q * 8 + j][ln]);
      ((bf16x8*)(dst + 64 + c0))[q] = o_.v;
    }
  }
}

// ---------------- K3: gathered conv (GEMM, K = 7*CIN), 2-phase dbuf DMA staging --------------
// Proven r1 skeleton (block-cooperative global_load_lds + __syncthreads, 16x16x32 MFMA,
// wave tile = 16 nodes x 64 outs) upgraded with:
//   * double-buffered A and W tiles; STAGE(kk+1) issued BEFORE compute(kk)  [m97 2-phase]
//   * ONE __syncthreads per kk (its implicit vmcnt(0) is the only DMA drain)
//   * full-width XOR swizzle slot^(row&(SLOTS-1)) -> conflict-free ds_read_b128
template <int CIN>
__global__ __launch_bounds__(256) void k_conv(const bf16* __restrict__ x,
                                              const int* __restrict__ neigh,
                                              const bf16* __restrict__ wp,
                                              const float* __restrict__ bias,
                                              bf16* __restrict__ y,
                                              float* __restrict__ partials) {
  constexpr int SLOTS = CIN / 8;             // 16B slots per row (16 or 8)
  constexpr int INSTR = (64 * CIN) / 512;    // 1KB DMA instrs per 64-row tile (16 or 8)
  constexpr int IPW   = INSTR / 4;           // DMA instrs per wave (4 or 2)
  constexpr int RPI   = 64 / INSTR;          // rows per DMA instr (4 or 8)
  constexpr int KS    = CIN / 32;            // MFMA K-steps per kk (4 or 2)
  constexpr int SWZ   = SLOTS - 1;

  __shared__ bf16 lA[2][64 * CIN];           // 2x16KB / 2x8KB
  __shared__ bf16 lW[2][64 * CIN];
  __shared__ int nbl[448];
  __shared__ float lred[4][2][64];

  int tid = threadIdx.x, b = blockIdx.y;
  int n0 = blockIdx.x * 64;
  int wv = tid >> 6, lane = tid & 63;
  int l15 = lane & 15, l4 = lane >> 4;

  for (int j = tid; j < 448; j += 256) {
    int gi = n0 * 7 + j;
    int gmax = NUP * 7 - 1;
    nbl[j] = neigh[gi <= gmax ? gi : gmax];
  }

  f32x4 acc[4];
#pragma unroll
  for (int ot = 0; ot < 4; ++ot) {
    float bv = bias[ot * 16 + l15];
    acc[ot] = (f32x4){bv, bv, bv, bv};
  }

  const bf16* xb = x + (size_t)b * NUP * CIN;
  const int r_in = lane / SLOTS;             // row within DMA instr
  const int s_in = lane % SLOTS;             // 16B slot within row

  auto STAGE_A = [&](int buf, int kk) {
#pragma unroll
    for (int i = 0; i < IPW; ++i) {
      int ii = wv * IPW + i;
      int r = ii * RPI + r_in;
      int g = s_in ^ (r & SWZ);
      int node = nbl[r * 7 + kk];
      gload_lds16(xb + (size_t)node * CIN + g * 8, &lA[buf][ii * 512]);
    }
  };
  auto STAGE_W = [&](int buf, int kk) {
#pragma unroll
    for (int i = 0; i < IPW; ++i) {
      int ii = wv * IPW + i;
      int r = ii * RPI + r_in;               // r = output row o
      int g = s_in ^ (r & SWZ);
      gload_lds16(wp + (size_t)r * (7 * CIN) + kk * CIN + g * 8, &lW[buf][ii * 512]);
    }
  };

  __syncthreads();                           // nbl ready
  STAGE_A(0, 0);
  STAGE_W(0, 0);
  __syncthreads();                           // stage(0) complete (implicit vmcnt(0))

  for (int kk = 0; kk < 7; ++kk) {
    int buf = kk & 1;
    if (kk < 6) { STAGE_A(buf ^ 1, kk + 1); STAGE_W(buf ^ 1, kk + 1); }
    // compute(kk): wave handles rows wv*16..+15, all 64 outs
    int r = wv * 16 + l15;
#pragma unroll
    for (int ks = 0; ks < KS; ++ks) {
      int sa = ks * 4 + l4;                  // k-slot index
      bf16x8 a = *(const bf16x8*)(&lA[buf][r * CIN + ((sa ^ (r & SWZ)) * 8)]);
#pragma unroll
      for (int ot = 0; ot < 4; ++ot) {
        int o = ot * 16 + l15;
        bf16x8 bb = *(const bf16x8*)(&lW[buf][o * CIN + ((sa ^ (o & SWZ)) * 8)]);
        acc[ot] = __builtin_amdgcn_mfma_f32_16x16x32_bf16(a, bb, acc[ot], 0, 0, 0);
      }
    }
    __syncthreads();                         // drains stage(kk+1) DMA; releases buf for overwrite
  }

  // store y (bf16) + per-channel partial sums (valid nodes only)
  float s[4], q[4];
#pragma unroll
  for (int ot = 0; ot < 4; ++ot) { s[ot] = 0.0f; q[ot] = 0.0f; }
  bf16* yb = y + (size_t)b * NUP * 64;
  int nodebase = n0 + wv * 16 + l4 * 4;
#pragma unroll
  for (int i = 0; i < 4; ++i) {
    int node = nodebase + i;
    bool ok = node < NUP;
#pragma unroll
    for (int ot = 0; ot < 4; ++ot) {
      float v = acc[ot][i];
      if (ok) {
        yb[(size_t)node * 64 + ot * 16 + l15] = __float2bfloat16(v);
        s[ot] += v; q[ot] += v * v;
      }
    }
  }
#pragma unroll
  for (int ot = 0; ot < 4; ++ot) {
    s[ot] += __shfl_xor(s[ot], 16); s[ot] += __shfl_xor(s[ot], 32);
    q[ot] += __shfl_xor(q[ot], 16); q[ot] += __shfl_xor(q[ot], 32);
  }
  if (lane < 16) {
#pragma unroll
    for (int ot = 0; ot < 4; ++ot) {
      lred[wv][0][ot * 16 + lane] = s[ot];
      lred[wv][1][ot * 16 + lane] = q[ot];
    }
  }
  __syncthreads();
  if (tid < 128) {
    int which = tid >> 6, c = tid & 63;
    float p = lred[0][which][c] + lred[1][which][c] + lred[2][which][c] + lred[3][which][c];
    partials[((size_t)b * gridDim.x + blockIdx.x) * 128 + which * 64 + c] = p;
  }
}

// ---------------- K4a: tree-reduce partials (nblk x 128) -> (128 x 128) ----------------------
__global__ __launch_bounds__(256) void k_red1(const float* __restrict__ p, int nblk,
                                              float* __restrict__ p2) {
  int g = blockIdx.x * 2 + threadIdx.x / 128;
  int j = threadIdx.x & 127;
  float a = 0.0f;
  for (int r = g; r < nblk; r += 128) a += p[(size_t)r * 128 + j];
  p2[(size_t)g * 128 + j] = a;
}

// ---------------- K4b: finalize BN: sc = g*rsqrt(var+eps), sh = beta - mean*sc ---------------
__global__ __launch_bounds__(128) void k_stats(const float* __restrict__ p2,
                                               const float* __restrict__ g,
                                               const float* __restrict__ be,
                                               float* __restrict__ sc, float* __restrict__ sh) {
  __shared__ double red[128];
  int j = threadIdx.x;
  double a = 0.0;
  for (int r = 0; r < 128; ++r) a += (double)p2[r * 128 + j];
  red[j] = a;
  __syncthreads();
  if (j < 64) {
    double M = (double)NBATCH * (double)NUP;
    double mean = red[j] / M;
    double var = red[64 + j] / M - mean * mean;
    float s = g[j] * (float)(1.0 / sqrt(var + BN_EPS));
    sc[j] = s;
    sh[j] = be[j] - (float)mean * s;
  }
}

// ---------------- K5: z = bf16(lrelu(y*sc + sh))  (y bf16 node-major) ------------------------
__global__ __launch_bounds__(256) void k_bnapply(const bf16* __restrict__ y,
                                                 const float* __restrict__ sc,
                                                 const float* __restrict__ sh,
                                                 bf16* __restrict__ z) {
  __shared__ float ssc[64], ssh[64];
  int tid = threadIdx.x;
  if (tid < 64) { ssc[tid] = sc[tid]; ssh[tid] = sh[tid]; }
  __syncthreads();
  size_t e = ((size_t)blockIdx.x * 256 + tid) * 8;
  if (e >= (size_t)NBATCH * NUP * 64) return;
  int c0 = (int)(e & 63);
  union { bf16x8 v; bf16 el[8]; } in_, o_;
  in_.v = *(const bf16x8*)(y + e);
#pragma unroll
  for (int j = 0; j < 8; ++j) {
    float f = __bfloat162float(in_.el[j]);
    o_.el[j] = __float2bfloat16(lrelu(fmaf(f, ssc[c0 + j], ssh[c0 + j])));
  }
  *(bf16x8*)(z + e) = o_.v;
}

// ---------------- K8: out[b,c,n] = lrelu(y[b,n,c]*sc+sh)  (transpose to channel-major) -------
__global__ __launch_bounds__(256) void k_final(const bf16* __restrict__ y,
                                               const float* __restrict__ sc,
                                               const float* __restrict__ sh,
                                               float* __restrict__ out) {
  __shared__ float t[64][65];
  __shared__ float ssc[64], ssh[64];
  int tid = threadIdx.x, b = blockIdx.y;
  int n0 = blockIdx.x * 64;
  if (tid < 64) { ssc[tid] = sc[tid]; ssh[tid] = sh[tid]; }
  __syncthreads();
  int ln = tid >> 2, qc = tid & 3;
  int n = n0 + ln; if (n >= NUP) n = NUP - 1;
  const bf16* yp = y + ((size_t)b * NUP + n) * 64 + qc * 16;
  union { bf16x8 v; bf16 el[8]; } v0, v1;
  v0.v = ((const bf16x8*)yp)[0];
  v1.v = ((const bf16x8*)yp)[1];
#pragma unroll
  for (int j = 0; j < 8; ++j) {
    int c = qc * 16 + j;
    t[ln][c] = lrelu(fmaf(__bfloat162float(v0.el[j]), ssc[c], ssh[c]));
  }
#pragma unroll
  for (int j = 0; j < 8; ++j) {
    int c = qc * 16 + 8 + j;
    t[ln][c] = lrelu(fmaf(__bfloat162float(v1.el[j]), ssc[c], ssh[c]));
  }
  __syncthreads();
  int nl = tid & 63;
  int nn = n0 + nl;
  if (nn >= NUP) return;
#pragma unroll
  for (int i = 0; i < 16; ++i) {
    int c = i * 4 + (tid >> 6);
    out[((size_t)b * 64 + c) * (size_t)NUP + nn] = t[nl][c];
  }
}

extern "C" void kernel_launch(void* const* d_in, const int* in_sizes, int n_in,
                              void* d_out, int out_size, void* d_ws, size_t ws_size,
                              hipStream_t stream) {
  const float* x1      = (const float*)d_in[0];
  const float* x2      = (const float*)d_in[1];
  const float* up_fc_w = (const float*)d_in[2];
  const float* up_fc_b = (const float*)d_in[3];
  const float* conv1_w = (const float*)d_in[4];
  const float* conv1_b = (const float*)d_in[5];
  const float* bn1_g   = (const float*)d_in[6];
  const float* bn1_b   = (const float*)d_in[7];
  const float* conv2_w = (const float*)d_in[8];
  const float* conv2_b = (const float*)d_in[9];
  const float* bn2_g   = (const float*)d_in[10];
  const float* bn2_b   = (const float*)d_in[11];
  const int* up_neigh  = (const int*)d_in[12];
  const int* conv_nei  = (const int*)d_in[13];

  char* ws = (char*)d_ws;
  bf16*  w1p  = (bf16*)(ws + OFF_W1P);
  bf16*  w2p  = (bf16*)(ws + OFF_W2P);
  float* sc   = (float*)(ws + OFF_STATS);
  float* sh   = sc + 64;
  bf16*  h    = (bf16*)(ws + OFF_H);
  float* part = (float*)(ws + OFF_H);      // aliases h (h dead after k_xcat)
  float* p2   = (float*)(ws + OFF_P2);
  bf16*  xcat = (bf16*)(ws + OFF_XCAT);
  bf16*  z1   = (bf16*)(ws + OFF_XCAT);    // aliases xcat (dead after conv1)
  bf16*  y    = (bf16*)(ws + OFF_Y);
  float* out  = (float*)d_out;

  k_permw<<<336, 256, 0, stream>>>(conv1_w, conv2_w, w1p, w2p);
  k_h<<<dim3(161, 2), 256, 0, stream>>>(x1, up_fc_w, up_fc_b, h);
  k_xcat<<<dim3(NT64, 2), 256, 0, stream>>>(x2, h, up_neigh, xcat);
  k_conv<128><<<dim3(NTC, 2), 256, 0, stream>>>(xcat, conv_nei, w1p, conv1_b, y, part);
  k_red1<<<64, 256, 0, stream>>>(part, 2 * NTC, p2);
  k_stats<<<1, 128, 0, stream>>>(p2, bn1_g, bn1_b, sc, sh);
  k_bnapply<<<10241, 256, 0, stream>>>(y, sc, sh, z1);
  k_conv<64><<<dim3(NTC, 2), 256, 0, stream>>>(z1, conv_nei, w2p, conv2_b, y, part);
  k_red1<<<64, 256, 0, stream>>>(part, 2 * NTC, p2);
  k_stats<<<1, 128, 0, stream>>>(p2, bn2_g, bn2_b, sc, sh);
  k_final<<<dim3(NT64, 2), 256, 0, stream>>>(y, sc, sh, out);
}